// Round 13
// baseline (1907.516 us; speedup 1.0000x reference)
//
#include <hip/hip_runtime.h>

#define B 64
#define T 256
#define H 512
#define G4 2048
#define D0 128
#define NL 6
#define NBLK_P 192            // 6 layers x 32 col-groups, 1 block/CU
#define GTOT (T + NL - 1)     // 261 global pipeline steps
#define FSTRIDE 16            // u32 stride between per-block flags (64B)
#define HSTR 1032             // h_s row stride, f16 units (1024 + 8 pad)
#define GSTR 36               // g_par row-dim stride, f32 (32 + 4)
#define RSLOT 32768           // f16 units per ring slot: 32 jblk x 64 b x 16 c

typedef float f32x4 __attribute__((ext_vector_type(4)));
typedef float f32x16 __attribute__((ext_vector_type(16)));
typedef unsigned uint4v __attribute__((ext_vector_type(4)));
typedef _Float16 h16x8 __attribute__((ext_vector_type(8)));

// Coherent 16B load/store (proven r9-r12): bypasses stale per-XCD L2.
#define CLOAD(dst, p) \
  asm volatile("global_load_dwordx4 %0, %1, off sc0 sc1" : "=&v"(dst) : "v"(p))
#define CSTORE4(p, v) \
  asm volatile("global_store_dwordx4 %0, %1, off sc0 sc1" :: "v"(p), "v"(v) : "memory")
#define VMWAIT do { asm volatile("s_waitcnt vmcnt(0)" ::: "memory"); \
                    __builtin_amdgcn_sched_barrier(0); } while (0)

// ===========================================================================
// lstm_pipe v5 — r12 + HBM-RMW elimination (layout-only; math bit-identical).
//  * Ring is BLOCKED: ring[l][slot][jblk][64 b][16 c] f16. A block's publish
//    is a contiguous 2KB region -> each wave's 64x2B stores coalesce into
//    full 128B lines (r12 wrote 32B fragments into 64 strided lines ->
//    partial-line write-through -> HBM RMW on the handoff path; the
//    measured 1.8 MB/step FETCH with an L3-resident working set).
//    Consumer map: 16B unit u -> (jblk=u>>1, half=u&1), LDS offset u*8 —
//    linear, so the staged h_s image is byte-identical to r12.
//  * Flags written as one full 64B line (lanes 0-3, dwordx4 each).
//  * Stage: issue all 8 CLOADs -> ONE vmcnt(0) drain -> all LDS writes.
//  * Everything else (W-in-reg 32x32x16 MFMA, g_par reduce, pointwise,
//    global flag barrier, l=0 tail skip, t=0 zero-fill): r12 verbatim.
// ===========================================================================
__global__ void __launch_bounds__(1024, 4) lstm_pipe(
    const float* __restrict__ x,
    const float* __restrict__ Wih0, const float* __restrict__ WihR,
    const float* __restrict__ Whh,
    const float* __restrict__ bih, const float* __restrict__ bhh,
    unsigned short* __restrict__ ring, float* __restrict__ h5,
    unsigned* __restrict__ flags)
{
  __shared__ unsigned short h_s[64 * HSTR];     // 132096 B
  float* const g_par = (float*)h_s;             // 73728 B, aliased

  const int tid  = threadIdx.x;
  const int lane = tid & 63;
  const int wl   = __builtin_amdgcn_readfirstlane(tid >> 6);
  const int ks   = wl & 3;                  // k-slice (256 k)
  const int rt   = (wl >> 2) >> 1;          // C row-tile (32 rows)
  const int bt   = (wl >> 2) & 1;           // C batch-tile (32 cols)
  const int blk  = (int)blockIdx.x;
  const int l    = blk >> 5;                // layer
  const int jb   = blk & 31;                // col-group id
  const int j0   = jb * 16;                 // owned cols j0..j0+15
  const int Kin  = (l == 0) ? D0 : H;
  const int KTOT = Kin + 512;               // 640 or 1024
  const int NU   = KTOT >> 3;               // 16B units per batch row

  const float* WihA = (l == 0) ? Wih0 : (WihR + (size_t)(l - 1) * G4 * H);
  const float* WhhA = Whh + (size_t)l * G4 * H;

  // ---- one-time: W slice -> A-fragments in registers (fp16) ----
  h16x8 a[16];
  {
    const int ri   = rt * 32 + (lane & 31);           // local row 0..63
    const int grow = (ri >> 4) * H + j0 + (ri & 15);  // gate*H + col
    const float* wihRow = WihA + (size_t)grow * Kin;
    const float* whhRow = WhhA + (size_t)grow * H;
    const int klane = (lane >> 5) * 8;
#pragma unroll
    for (int m = 0; m < 16; ++m) {
      int kb = ks * 256 + m * 16;
      h16x8 f = {};
      if (kb < KTOT) {
        const float* src = (kb < Kin) ? (wihRow + kb + klane)
                                      : (whhRow + (kb - Kin) + klane);
        f32x4 v0 = *(const f32x4*)src;
        f32x4 v1 = *(const f32x4*)(src + 4);
        f[0] = (_Float16)v0.x; f[1] = (_Float16)v0.y;
        f[2] = (_Float16)v0.z; f[3] = (_Float16)v0.w;
        f[4] = (_Float16)v1.x; f[5] = (_Float16)v1.y;
        f[6] = (_Float16)v1.z; f[7] = (_Float16)v1.w;
      }
      a[m] = f;
    }
  }

  // pointwise ownership + bias
  const int pb = tid >> 4, pcj = tid & 15;
  float bias4[4];
#pragma unroll
  for (int gi = 0; gi < 4; ++gi) {
    int grow = gi * H + j0 + pcj;
    bias4[gi] = bih[(size_t)l * G4 + grow] + bhh[(size_t)l * G4 + grow];
  }

  // stage mapping: thread -> (batch row sb, base unit u0)
  const int sb = tid >> 4, u0 = tid & 15;
  float creg = 0.f;

  for (int g = 0; g < GTOT; ++g) {
    const int t = g - l;
    const bool active = (t >= 0) && (t < T);

    if (g > 0) {   // wait: all blocks finished step g-1 (proven flag array)
      if (tid < NBLK_P) {
        while (__hip_atomic_load(&flags[tid * FSTRIDE], __ATOMIC_RELAXED,
                                 __HIP_MEMORY_SCOPE_AGENT) < (unsigned)g)
          __builtin_amdgcn_s_sleep(1);
      }
      __syncthreads();
    }

    if (active) {
      // ---- stage h_cat = [inA | inB] as f16 into h_s (blocked ring) ----
      const unsigned short* rgA = ring + ((size_t)(l - 1) * 2 + (t & 1)) * RSLOT;
      const unsigned short* rgB = ring + ((size_t)l * 2 + ((t - 1) & 1)) * RSLOT;
      unsigned short* dst = &h_s[sb * HSTR];

      if (l == 0) {    // x region: units 0..15, f32 -> f16 cvt
        const float* xr = x + ((size_t)sb * T + t) * D0 + u0 * 8;
        f32x4 v0 = *(const f32x4*)xr, v1 = *(const f32x4*)(xr + 4);
        h16x8 hv;
        hv[0] = (_Float16)v0.x; hv[1] = (_Float16)v0.y;
        hv[2] = (_Float16)v0.z; hv[3] = (_Float16)v0.w;
        hv[4] = (_Float16)v1.x; hv[5] = (_Float16)v1.y;
        hv[6] = (_Float16)v1.z; hv[7] = (_Float16)v1.w;
        *(h16x8*)&dst[u0 * 8] = hv;
      }
      const int i0  = (l == 0) ? 1 : 0;
      const int nIt = NU >> 4;       // 5 (l=0) or 8
      f32x4 rr[8];
#pragma unroll
      for (int i = 0; i < 8; ++i) {
        if (i < i0 || i >= nIt) continue;
        int u = u0 + 16 * i;
        int ub; const unsigned short* rg; bool isB;
        if (l == 0)      { ub = u - 16; rg = rgB; isB = true;  }
        else if (u < 64) { ub = u;      rg = rgA; isB = false; }
        else             { ub = u - 64; rg = rgB; isB = true;  }
        if (isB && t == 0) { f32x4 z = {0.f, 0.f, 0.f, 0.f}; rr[i] = z; }
        else CLOAD(rr[i], rg + (ub >> 1) * 1024 + sb * 16 + (ub & 1) * 8);
      }
      VMWAIT;
#pragma unroll
      for (int i = 0; i < 8; ++i) {
        if (i < i0 || i >= nIt) continue;
        int u = u0 + 16 * i;
        *(f32x4*)&dst[u * 8] = rr[i];
      }
      __syncthreads();

      // ---- 16 MFMAs: wave's (rt,bt) tile x its 256-k slice ----
      f32x16 accv = {};
      const unsigned short* brow =
          &h_s[(bt * 32 + (lane & 31)) * HSTR + ks * 256 + (lane >> 5) * 8];
#pragma unroll
      for (int m = 0; m < 16; ++m) {
        if (ks * 256 + m * 16 < KTOT) {        // wave-uniform skip (l=0 tail)
          h16x8 b8 = *(const h16x8*)(brow + m * 16);
          accv = __builtin_amdgcn_mfma_f32_32x32x16_f16(a[m], b8, accv, 0, 0, 0);
        }
      }
      __syncthreads();   // all B-reads done -> g_par may alias h_s

      // ---- k-slice partials -> g_par (b128, slot-uniform) ----
      {
        float* gp = g_par +
            (size_t)((ks * 4 + (rt * 2 + bt)) * 32 + (lane & 31)) * GSTR +
            4 * (lane >> 5);
#pragma unroll
        for (int q = 0; q < 4; ++q) {
          f32x4 tv;
          tv.x = accv[4 * q];     tv.y = accv[4 * q + 1];
          tv.z = accv[4 * q + 2]; tv.w = accv[4 * q + 3];
          *(f32x4*)&gp[8 * q] = tv;    // rows 8q + 4*(lane>>5) + 0..3
        }
      }
      __syncthreads();

      // ---- reduce + bias + pointwise + publish (full-line, blocked) ----
      {
        float gt[4];
#pragma unroll
        for (int gi = 0; gi < 4; ++gi) {
          int rowL = gi * 16 + pcj;
          int tile = (rowL >> 5) * 2 + (pb >> 5);
          int rL   = rowL & 31;
          float s = bias4[gi];
#pragma unroll
          for (int ksi = 0; ksi < 4; ++ksi)
            s += g_par[(size_t)((ksi * 4 + tile) * 32 + (pb & 31)) * GSTR + rL];
          gt[gi] = s;
        }
        float iv = 1.f / (1.f + expf(-gt[0]));
        float fv = 1.f / (1.f + expf(-gt[1]));
        float gv = tanhf(gt[2]);
        float ov = 1.f / (1.f + expf(-gt[3]));
        creg = fv * creg + iv * gv;
        float hv = ov * tanhf(creg);
        _Float16 hf = (_Float16)hv;
        // blocked ring: block's 2KB region, wave-contiguous -> full lines
        size_t pA = ((size_t)(l * 2 + (t & 1)) * 32 + jb) * 1024 + pb * 16 + pcj;
        __hip_atomic_store(&ring[pA], __builtin_bit_cast(unsigned short, hf),
                           __ATOMIC_RELAXED, __HIP_MEMORY_SCOPE_AGENT);
        if (l == NL - 1 && t == T - 1)
          h5[pb * H + j0 + pcj] = hv;    // f32 copy for FC precision
      }
      __syncthreads();   // drain publish stores before flagging
    }

    // full-line flag write: lanes 0-3, one dwordx4 each (64B covered)
    if (tid < 4) {
      uint4v fv;
      fv[0] = fv[1] = fv[2] = fv[3] = (unsigned)(g + 1);
      CSTORE4(&flags[blk * FSTRIDE + tid * 4], fv);
    }
  }
}

// ===========================================================================
// Final FC on h_5(T-1) (f32 side buffer)
// ===========================================================================
__global__ void __launch_bounds__(640) fc_kernel(
    const float* __restrict__ h5, const float* __restrict__ w,
    const float* __restrict__ bias, float* __restrict__ out)
{
  int tid = threadIdx.x;
  if (tid >= 640) return;
  int b = tid / 10, o = tid - b * 10;
  const float* yr = h5 + (size_t)b * H;
  const float* wr = w + (size_t)o * H;
  float acc = bias[o];
  for (int k = 0; k < H; ++k) acc = fmaf(yr[k], wr[k], acc);
  out[b * 10 + o] = acc;
}

extern "C" void kernel_launch(void* const* d_in, const int* in_sizes, int n_in,
                              void* d_out, int out_size, void* d_ws,
                              size_t ws_size, hipStream_t stream)
{
  const float* x    = (const float*)d_in[0];
  const float* Wih0 = (const float*)d_in[1];
  const float* WihR = (const float*)d_in[2];
  const float* Whh  = (const float*)d_in[3];
  const float* bih  = (const float*)d_in[4];
  const float* bhh  = (const float*)d_in[5];
  const float* fcw  = (const float*)d_in[6];
  const float* fcb  = (const float*)d_in[7];
  float* out = (float*)d_out;

  // ws: [0,16K) flags; blocked ring f16[6][2][32][64][16] (768 KB); h5 f32
  unsigned* flags = (unsigned*)d_ws;
  unsigned short* ring = (unsigned short*)((char*)d_ws + 16384);
  float* h5buf = (float*)((char*)d_ws + 16384 + (size_t)NL * 2 * RSLOT * 2);

  hipMemsetAsync(d_ws, 0, 16384, stream);   // flags monotonic within a call

  lstm_pipe<<<NBLK_P, 1024, 0, stream>>>(x, Wih0, WihR, Whh, bih, bhh,
                                         ring, h5buf, flags);
  fc_kernel<<<1, 640, 0, stream>>>(h5buf, fcw, fcb, out);
}